// Round 7
// baseline (24.197 us; speedup 1.0000x reference)
//
#include <hip/hip_runtime.h>

constexpr int N    = 8192;
constexpr int BLK  = 256;
constexpr int BX   = 128;      // x-points per block
constexpr int BY   = 1024;     // y-points per block (one y-range)
constexpr int NYR  = N / BY;   // 8 y-ranges
constexpr int P    = 8;        // x-points per thread
constexpr int NSL  = 16;       // y-slices per block
constexpr int SY   = BY / NSL; // 64 y per slice
constexpr int SPAD = SY + 1;   // 65 float4s: +4 banks per slice
constexpr int RPAD = BX + 4;   // 132: +4 banks per slice row

// grid 1024 (4 blocks/CU, 4 waves/SIMD): dir = b>>9, xbk = (b>>3)&63, yr = b&7.
// Thread (u = t&15, ys = t>>4) owns x {xbk*128 + k*16 + u} and scans y-slice ys
// (64 pts) from LDS. 128 partial mins per block -> minbuf[yr][dir*N + x].
__global__ __launch_bounds__(BLK) void chamfer_stage1(
    const float* __restrict__ pred, const float* __restrict__ label,
    float* __restrict__ minbuf)
{
    int b   = blockIdx.x;
    int dir = b >> 9;
    int xbk = (b >> 3) & 63;
    int yr  = b & 7;

    const float* A = dir ? label : pred;   // query set
    const float* B = dir ? pred  : label;  // target set

    __shared__ float4 sy[NSL * SPAD];      // 16.6 KB
    __shared__ float  red[NSL * RPAD];     // 8.4 KB

    int u  = threadIdx.x & 15;
    int ys = threadIdx.x >> 4;

    float xa[P], xb[P], xc[P], nx[P], m[P];
    #pragma unroll
    for (int k = 0; k < P; ++k) {
        int idx = xbk * BX + k * 16 + u;
        float a = A[3*idx], c = A[3*idx+1], d = A[3*idx+2];
        xa[k] = -2.f * a;  xb[k] = -2.f * c;  xc[k] = -2.f * d;
        nx[k] = a*a + c*c + d*d;
        m[k]  = 3.4e38f;
    }

    for (int i = threadIdx.x; i < BY; i += BLK) {
        int g = yr * BY + i;
        float a = B[3*g], c = B[3*g+1], d = B[3*g+2];
        sy[(i / SY) * SPAD + (i & (SY-1))] = make_float4(a, c, d, a*a + c*c + d*d);
    }
    __syncthreads();

    const float4* s = &sy[ys * SPAD];
    #pragma unroll 4
    for (int j = 0; j < SY; j += 2) {
        float4 ya = s[j], yb = s[j + 1];
        #pragma unroll
        for (int k = 0; k < P; ++k) {
            float sa = fmaf(xa[k], ya.x, fmaf(xb[k], ya.y, fmaf(xc[k], ya.z, ya.w)));
            float sb = fmaf(xa[k], yb.x, fmaf(xb[k], yb.y, fmaf(xc[k], yb.z, yb.w)));
            m[k] = fminf(fminf(sa, sb), m[k]);   // v_min3_f32
        }
    }

    #pragma unroll
    for (int k = 0; k < P; ++k)
        red[ys * RPAD + k * 16 + u] = fmaxf(m[k] + nx[k], 0.f);
    __syncthreads();

    if (threadIdx.x < BX) {
        float v = red[threadIdx.x];
        #pragma unroll
        for (int q = 1; q < NSL; ++q)
            v = fminf(v, red[q * RPAD + threadIdx.x]);
        minbuf[yr * (2 * N) + dir * N + xbk * BX + threadIdx.x] = v;
    }
}

// One 1024-thread block: float4 min over 8 y-ranges (coalesced), sqrt, mean.
__global__ __launch_bounds__(1024) void chamfer_stage2(
    const float4* __restrict__ minbuf4, float* __restrict__ out)
{
    float s = 0.f;
    #pragma unroll
    for (int j = 0; j < (2 * N / 4) / 1024; ++j) {      // 4 iters
        int g = j * 1024 + threadIdx.x;                 // float4 index in [0, 4096)
        float4 v = minbuf4[g];
        #pragma unroll
        for (int r = 1; r < NYR; ++r) {
            float4 w = minbuf4[r * 4096 + g];
            v.x = fminf(v.x, w.x); v.y = fminf(v.y, w.y);
            v.z = fminf(v.z, w.z); v.w = fminf(v.w, w.w);
        }
        s += sqrtf(v.x) + sqrtf(v.y) + sqrtf(v.z) + sqrtf(v.w);
    }
    s *= (1.0f / N);
    for (int off = 32; off; off >>= 1) s += __shfl_down(s, off);
    __shared__ float r2[16];
    if ((threadIdx.x & 63) == 0) r2[threadIdx.x >> 6] = s;
    __syncthreads();
    if (threadIdx.x == 0) {
        float v = 0.f;
        #pragma unroll
        for (int i = 0; i < 16; ++i) v += r2[i];
        out[0] = v;            // mean_x(min) + mean_y(min)
    }
}

extern "C" void kernel_launch(void* const* d_in, const int* in_sizes, int n_in,
                              void* d_out, int out_size, void* d_ws, size_t ws_size,
                              hipStream_t stream) {
    const float* pred  = (const float*)d_in[0];
    const float* label = (const float*)d_in[1];
    float* out    = (float*)d_out;
    float* minbuf = (float*)d_ws;   // NYR * 2N floats = 512 KB, fully rewritten

    chamfer_stage1<<<dim3(2 * (N / BX) * NYR), dim3(BLK),  0, stream>>>(pred, label, minbuf);
    chamfer_stage2<<<dim3(1), dim3(1024), 0, stream>>>((const float4*)minbuf, out);
}

// Round 8
// 19.694 us; speedup vs baseline: 1.2287x; 1.2287x over previous
//
#include <hip/hip_runtime.h>

constexpr int N    = 8192;
constexpr int BLK  = 256;
constexpr int BX   = 128;      // x-points per block
constexpr int BY   = 2048;     // y-points per block (one y-range)
constexpr int NYR  = N / BY;   // 4 y-ranges
constexpr int P    = 8;        // x-points per thread
constexpr int NSL  = 16;       // y-slices per block
constexpr int SY   = BY / NSL; // 128 y per slice
constexpr int SPAD = SY + 1;   // 129 float4s: +4 banks per slice
constexpr int RPAD = BX + 4;   // 132: +4 banks per slice row

// grid 512: dir = b>>8, xbk = (b>>2)&63, yr = b&3.  (identical to Round 6)
__global__ __launch_bounds__(BLK) void chamfer_stage1(
    const float* __restrict__ pred, const float* __restrict__ label,
    float* __restrict__ minbuf)
{
    int b   = blockIdx.x;
    int dir = b >> 8;
    int xbk = (b >> 2) & 63;
    int yr  = b & 3;

    const float* A = dir ? label : pred;   // query set
    const float* B = dir ? pred  : label;  // target set

    __shared__ float4 sy[NSL * SPAD];      // 33 KB
    __shared__ float  red[NSL * RPAD];     // 8.4 KB

    int u  = threadIdx.x & 15;
    int ys = threadIdx.x >> 4;

    float xa[P], xb[P], xc[P], nx[P], m[P];
    #pragma unroll
    for (int k = 0; k < P; ++k) {
        int idx = xbk * BX + k * 16 + u;
        float a = A[3*idx], c = A[3*idx+1], d = A[3*idx+2];
        xa[k] = -2.f * a;  xb[k] = -2.f * c;  xc[k] = -2.f * d;
        nx[k] = a*a + c*c + d*d;
        m[k]  = 3.4e38f;
    }

    for (int i = threadIdx.x; i < BY; i += BLK) {
        int g = yr * BY + i;
        float a = B[3*g], c = B[3*g+1], d = B[3*g+2];
        sy[(i >> 7) * SPAD + (i & (SY-1))] = make_float4(a, c, d, a*a + c*c + d*d);
    }
    __syncthreads();

    const float4* s = &sy[ys * SPAD];
    #pragma unroll 4
    for (int j = 0; j < SY; j += 2) {
        float4 ya = s[j], yb = s[j + 1];
        #pragma unroll
        for (int k = 0; k < P; ++k) {
            float sa = fmaf(xa[k], ya.x, fmaf(xb[k], ya.y, fmaf(xc[k], ya.z, ya.w)));
            float sb = fmaf(xa[k], yb.x, fmaf(xb[k], yb.y, fmaf(xc[k], yb.z, yb.w)));
            m[k] = fminf(fminf(sa, sb), m[k]);   // v_min3_f32
        }
    }

    #pragma unroll
    for (int k = 0; k < P; ++k)
        red[ys * RPAD + k * 16 + u] = fmaxf(m[k] + nx[k], 0.f);
    __syncthreads();

    if (threadIdx.x < BX) {
        float v = red[threadIdx.x];
        #pragma unroll
        for (int q = 1; q < NSL; ++q)
            v = fminf(v, red[q * RPAD + threadIdx.x]);
        minbuf[yr * (2 * N) + dir * N + xbk * BX + threadIdx.x] = v;
    }
}

// 16 blocks x 256 threads: each thread one float4 column, min over 4 ranges
// (coalesced 16 B/lane), sqrt, fixed-order block sum -> bsum[block].
__global__ __launch_bounds__(256) void chamfer_stage2(
    const float4* __restrict__ minbuf4, float* __restrict__ bsum)
{
    int g = blockIdx.x * 256 + threadIdx.x;   // float4 index in [0, 4096)
    float4 v = minbuf4[g];
    #pragma unroll
    for (int r = 1; r < NYR; ++r) {
        float4 w = minbuf4[r * 4096 + g];
        v.x = fminf(v.x, w.x); v.y = fminf(v.y, w.y);
        v.z = fminf(v.z, w.z); v.w = fminf(v.w, w.w);
    }
    float s = sqrtf(v.x) + sqrtf(v.y) + sqrtf(v.z) + sqrtf(v.w);
    for (int off = 32; off; off >>= 1) s += __shfl_down(s, off);
    __shared__ float r2[4];
    if ((threadIdx.x & 63) == 0) r2[threadIdx.x >> 6] = s;
    __syncthreads();
    if (threadIdx.x == 0)
        bsum[blockIdx.x] = r2[0] + r2[1] + r2[2] + r2[3];
}

// one wave: final fixed-order sum of 16 block partials, scale by 1/N.
__global__ __launch_bounds__(64) void chamfer_stage3(
    const float* __restrict__ bsum, float* __restrict__ out)
{
    float s = (threadIdx.x < 16) ? bsum[threadIdx.x] : 0.f;
    for (int off = 32; off; off >>= 1) s += __shfl_down(s, off);
    if (threadIdx.x == 0) out[0] = s * (1.0f / N);   // mean_x(min)+mean_y(min)
}

extern "C" void kernel_launch(void* const* d_in, const int* in_sizes, int n_in,
                              void* d_out, int out_size, void* d_ws, size_t ws_size,
                              hipStream_t stream) {
    const float* pred  = (const float*)d_in[0];
    const float* label = (const float*)d_in[1];
    float* out    = (float*)d_out;
    float* minbuf = (float*)d_ws;                 // NYR*2N floats = 256 KB
    float* bsum   = minbuf + NYR * 2 * N;         // 16 floats

    chamfer_stage1<<<dim3(2 * (N / BX) * NYR), dim3(BLK), 0, stream>>>(pred, label, minbuf);
    chamfer_stage2<<<dim3(16), dim3(256), 0, stream>>>((const float4*)minbuf, bsum);
    chamfer_stage3<<<dim3(1), dim3(64), 0, stream>>>(bsum, out);
}